// Round 12
// baseline (531.742 us; speedup 1.0000x reference)
//
#include <hip/hip_runtime.h>
#include <hip/hip_bf16.h>

typedef __attribute__((ext_vector_type(8))) short bf16x8;
typedef __attribute__((ext_vector_type(4))) float f32x4;

#define NB 16384
#define NE 31

static __device__ __forceinline__ unsigned short f2b(float f) {
  unsigned int u = __builtin_bit_cast(unsigned int, f);
  return (unsigned short)((u + 0x7fffu + ((u >> 16) & 1u)) >> 16);
}
static __device__ __forceinline__ float b2f(unsigned short h) {
  return __builtin_bit_cast(float, ((unsigned int)h) << 16);
}
static __device__ __forceinline__ unsigned int cvtpk(float a, float b) {
  unsigned int r;
  asm("v_cvt_pk_bf16_f32 %0, %1, %2" : "=v"(r) : "v"(a), "v"(b));
  return r;
}

// ---------------------------------------------------------------------------
// k0_all: weight preprocessing (one launch).
// W1 (bf16 [1792][256]): rows 0..255 = 0.125*Wq; 256..511 = Wk; 512..767 = Wv;
//   rows 768..1791 = Wqo[h*256+c][k] = sum_d 0.125*Wq[h*64+d][k]*Wok[h*64+d][c]
// W2 (bf16 [256][1280]): row n: cols h*256+c = sum_d Wov[h*64+d][c]*Wc[n][h*64+d];
//   cols 1024+m = Wc[n][m]
// ---------------------------------------------------------------------------
__global__ void k0_all(const float* __restrict__ wq, const float* __restrict__ wk,
                       const float* __restrict__ wv, const float* __restrict__ wok,
                       const float* __restrict__ wov, const float* __restrict__ wc,
                       unsigned short* __restrict__ W1, unsigned short* __restrict__ W2) {
  int r = blockIdx.x, k = threadIdx.x;
  if (r < 1024) {
    if (r < 256) {
      W1[r * 256 + k] = f2b(0.125f * wq[r * 256 + k]);
    } else if (r < 512) {
      W1[r * 256 + k] = f2b(wk[(r - 256) * 256 + k]);
    } else if (r < 768) {
      W1[r * 256 + k] = f2b(wv[(r - 512) * 256 + k]);
    } else {
      int n = r - 768;
      W2[n * 1280 + 1024 + k] = f2b(wc[n * 256 + k]);
    }
  } else if (r < 2048) {
    int m = r - 1024;  // 0..1023
    int h = m >> 8, c = m & 255;
    float acc = 0.f;
#pragma unroll 8
    for (int d = 0; d < 64; ++d)
      acc = fmaf(wq[(h * 64 + d) * 256 + k], wok[(h * 64 + d) * 256 + c], acc);
    W1[(768 + m) * 256 + k] = f2b(0.125f * acc);
  } else {
    int n = r - 2048;  // 0..255
#pragma unroll 1
    for (int mi = 0; mi < 4; ++mi) {
      float acc = 0.f;
#pragma unroll 8
      for (int d = 0; d < 64; ++d)
        acc = fmaf(wov[(mi * 64 + d) * 256 + k], wc[n * 256 + mi * 64 + d], acc);
      W2[n * 1280 + mi * 256 + k] = f2b(acc);
    }
  }
}

// ---------------------------------------------------------------------------
// k1b: qkv2[b][n] = sum_k ego[b][k] * W1[n][k]. bf16 out. (round-7 shape)
// 512 blocks: (row-group 64) x (col-half 896); 2 blocks/CU.
// ---------------------------------------------------------------------------
__global__ __launch_bounds__(256, 2)
void k1b(const float* __restrict__ ego, const unsigned short* __restrict__ W1,
         unsigned short* __restrict__ qkv2) {
  __shared__ __align__(16) unsigned short Al[64 * 256];  // 32KB, swizzled
  const int tid = threadIdx.x;
  const int bM = (blockIdx.x >> 1) * 64;
  const int half = (blockIdx.x & 1) * 896;
#pragma unroll
  for (int it = 0; it < 8; ++it) {
    int c = tid + it * 256;                // 2048 chunks of 8 f32
    int row = c >> 5, k8 = c & 31;
    const float4* g = (const float4*)(ego + (size_t)(bM + row) * 256 + k8 * 8);
    float4 x = g[0], y = g[1];
    float t[8] = {x.x, x.y, x.z, x.w, y.x, y.y, y.z, y.w};
    bf16x8 v;
#pragma unroll
    for (int j = 0; j < 8; ++j) v[j] = (short)f2b(t[j]);
    int byteoff = row * 512 + ((k8 * 16) ^ ((row & 7) << 4));
    *(bf16x8*)((char*)Al + byteoff) = v;
  }
  __syncthreads();
  const int w = tid >> 6, lane = tid & 63, lr = lane & 15, lkg = lane >> 4;
#pragma unroll 1
  for (int cb = 0; cb < 7; ++cb) {
    int bN = half + w * 224 + cb * 32;
    f32x4 acc[4][2];
#pragma unroll
    for (int mt = 0; mt < 4; ++mt)
#pragma unroll
      for (int nt = 0; nt < 2; ++nt) acc[mt][nt] = (f32x4){0.f, 0.f, 0.f, 0.f};
#pragma unroll
    for (int kk = 0; kk < 8; ++kk) {
      int kidx = kk * 32 + lkg * 8;
      bf16x8 bfr[2];
#pragma unroll
      for (int nt = 0; nt < 2; ++nt)
        bfr[nt] = *(const bf16x8*)(W1 + (size_t)(bN + nt * 16 + lr) * 256 + kidx);
#pragma unroll
      for (int mt = 0; mt < 4; ++mt) {
        int row = mt * 16 + lr;
        int byteoff = row * 512 + ((kidx * 2) ^ ((row & 7) << 4));
        bf16x8 a = *(const bf16x8*)((const char*)Al + byteoff);
#pragma unroll
        for (int nt = 0; nt < 2; ++nt)
          acc[mt][nt] = __builtin_amdgcn_mfma_f32_16x16x32_bf16(a, bfr[nt], acc[mt][nt], 0, 0, 0);
      }
    }
#pragma unroll
    for (int mt = 0; mt < 4; ++mt)
#pragma unroll
      for (int nt = 0; nt < 2; ++nt)
#pragma unroll
        for (int j = 0; j < 4; ++j) {
          int row = bM + mt * 16 + lkg * 4 + j;
          int col = bN + nt * 16 + lr;
          qkv2[(size_t)row * 1792 + col] = f2b(acc[mt][nt][j]);
        }
  }
}

// ---------------------------------------------------------------------------
// ks_attn: ONE 64-THREAD BLOCK = ONE ITEM (round-10 version).
// ---------------------------------------------------------------------------
__global__ __launch_bounds__(64, 4)
void ks_attn(const float* __restrict__ others, const int* __restrict__ mask,
             const unsigned short* __restrict__ qkv2,
             unsigned short* __restrict__ u,
             float* __restrict__ attnout) {
  __shared__ __align__(16) unsigned short Xs[8192];  // exactly 16KB
  const int lane = threadIdx.x;                      // 0..63
  const int lr = lane & 15, lkg = lane >> 4;
  const size_t b = blockIdx.x;
  char* Xc = (char*)Xs;
  const unsigned short* qk = qkv2 + b * 1792;

  bf16x8 af[8];
#pragma unroll
  for (int kk = 0; kk < 8; ++kk)
    af[kk] = *(const bf16x8*)(qk + 768 + (lr & 3) * 256 + kk * 32 + lkg * 8);
  ushort4 qa = *(const ushort4*)(qk + lkg * 64 + lr * 4);
  ushort4 kb = *(const ushort4*)(qk + 256 + lkg * 64 + lr * 4);
  ushort4 ve = *(const ushort4*)(qk + 512 + lane * 4);
  int mk0 = mask[b * 32 + 1 + lr];
  int mk1 = (lr == 15) ? 1 : mask[b * 32 + 17 + lr];
  int mkE = mask[b * 32];

  {
    const char* src = (const char*)(others + b * (NE * 256)) + lane * 16;
#pragma unroll
    for (int j = 0; j < NE; ++j) {
      float4 f = *(const float4*)(src + j * 1024);
      uint2 v;
      v.x = cvtpk(f.x, f.y);
      v.y = cvtpk(f.z, f.w);
      *(uint2*)(Xc + j * 512 + ((lane * 8) ^ ((j & 15) << 4))) = v;
    }
    uint2 z; z.x = 0; z.y = 0;
    *(uint2*)(Xc + 31 * 512 + ((lane * 8) ^ ((31 & 15) << 4))) = z;
  }

  float s0p = b2f(qa.x) * b2f(kb.x) + b2f(qa.y) * b2f(kb.y) +
              b2f(qa.z) * b2f(kb.z) + b2f(qa.w) * b2f(kb.w);
#pragma unroll
  for (int off = 1; off < 16; off <<= 1) s0p += __shfl_xor(s0p, off, 16);
  float s0h[4];
  s0h[0] = __shfl(s0p, 0);
  s0h[1] = __shfl(s0p, 16);
  s0h[2] = __shfl(s0p, 32);
  s0h[3] = __shfl(s0p, 48);

  asm volatile("s_waitcnt lgkmcnt(0)" ::: "memory");
  __builtin_amdgcn_sched_barrier(0);

  f32x4 acc0 = (f32x4){0.f, 0.f, 0.f, 0.f};
  f32x4 acc1 = (f32x4){0.f, 0.f, 0.f, 0.f};
#pragma unroll
  for (int kk = 0; kk < 8; ++kk) {
    int co = kk * 64 + lkg * 16;
    bf16x8 b0 = *(const bf16x8*)(Xc + lr * 512 + (co ^ (lr << 4)));
    bf16x8 b1 = *(const bf16x8*)(Xc + (16 + lr) * 512 + (co ^ (lr << 4)));
    acc0 = __builtin_amdgcn_mfma_f32_16x16x32_bf16(af[kk], b0, acc0, 0, 0, 0);
    acc1 = __builtin_amdgcn_mfma_f32_16x16x32_bf16(af[kk], b1, acc1, 0, 0, 0);
  }

  float pr0[4], pr1[4], p0v[4];
#pragma unroll
  for (int j = 0; j < 4; ++j) {
    float sj0 = mk0 ? -1e9f : acc0[j];
    float sj1 = mk1 ? -1e9f : acc1[j];
    float se  = mkE ? -1e9f : s0h[j];
    float mx = fmaxf(se, fmaxf(sj0, sj1));
#pragma unroll
    for (int off = 1; off < 16; off <<= 1) mx = fmaxf(mx, __shfl_xor(mx, off, 16));
    float e0 = __expf(sj0 - mx), e1 = __expf(sj1 - mx), ee = __expf(se - mx);
    float sm = e0 + e1;
#pragma unroll
    for (int off = 1; off < 16; off <<= 1) sm += __shfl_xor(sm, off, 16);
    float rinv = 1.f / (sm + ee);
    pr0[j] = e0 * rinv;
    pr1[j] = e1 * rinv;
    p0v[j] = ee * rinv;
  }
  if (lkg == 0) {
#pragma unroll
    for (int j = 0; j < 4; ++j) {
      attnout[b * 128 + j * 32 + 1 + lr] = pr0[j];
      if (lr < 15) attnout[b * 128 + j * 32 + 17 + lr] = pr1[j];
      if (lr == 0) attnout[b * 128 + j * 32] = p0v[j];
    }
  }

  f32x4 cx[4];
#pragma unroll
  for (int h = 0; h < 4; ++h) cx[h] = (f32x4){0.f, 0.f, 0.f, 0.f};
#pragma unroll
  for (int e = 0; e < NE; ++e) {
    float p0, p1, p2, p3;
    if (e < 16) {
      p0 = __shfl(pr0[0], e); p1 = __shfl(pr0[1], e);
      p2 = __shfl(pr0[2], e); p3 = __shfl(pr0[3], e);
    } else {
      p0 = __shfl(pr1[0], e - 16); p1 = __shfl(pr1[1], e - 16);
      p2 = __shfl(pr1[2], e - 16); p3 = __shfl(pr1[3], e - 16);
    }
    ushort4 xr = *(const ushort4*)(Xc + e * 512 + ((lane * 8) ^ ((e & 15) << 4)));
    float x0 = b2f(xr.x), x1 = b2f(xr.y), x2 = b2f(xr.z), x3 = b2f(xr.w);
    cx[0][0] = fmaf(p0, x0, cx[0][0]); cx[0][1] = fmaf(p0, x1, cx[0][1]);
    cx[0][2] = fmaf(p0, x2, cx[0][2]); cx[0][3] = fmaf(p0, x3, cx[0][3]);
    cx[1][0] = fmaf(p1, x0, cx[1][0]); cx[1][1] = fmaf(p1, x1, cx[1][1]);
    cx[1][2] = fmaf(p1, x2, cx[1][2]); cx[1][3] = fmaf(p1, x3, cx[1][3]);
    cx[2][0] = fmaf(p2, x0, cx[2][0]); cx[2][1] = fmaf(p2, x1, cx[2][1]);
    cx[2][2] = fmaf(p2, x2, cx[2][2]); cx[2][3] = fmaf(p2, x3, cx[2][3]);
    cx[3][0] = fmaf(p3, x0, cx[3][0]); cx[3][1] = fmaf(p3, x1, cx[3][1]);
    cx[3][2] = fmaf(p3, x2, cx[3][2]); cx[3][3] = fmaf(p3, x3, cx[3][3]);
  }
#pragma unroll
  for (int h = 0; h < 4; ++h) {
    ushort4 st;
    st.x = f2b(cx[h][0]); st.y = f2b(cx[h][1]);
    st.z = f2b(cx[h][2]); st.w = f2b(cx[h][3]);
    *(ushort4*)(u + b * 1280 + h * 256 + lane * 4) = st;
  }
  {
    float p0h = (lkg == 0) ? p0v[0] : (lkg == 1) ? p0v[1] : (lkg == 2) ? p0v[2] : p0v[3];
    ushort4 sv;
    sv.x = f2b(p0h * b2f(ve.x)); sv.y = f2b(p0h * b2f(ve.y));
    sv.z = f2b(p0h * b2f(ve.z)); sv.w = f2b(p0h * b2f(ve.w));
    *(ushort4*)(u + b * 1280 + 1024 + lane * 4) = sv;
  }
}

// ---------------------------------------------------------------------------
// k4: res[b][n] = (sum_m u[b][m]*W2[n][m] + ego[b][n]) * 0.5  (round-7 shape)
// ---------------------------------------------------------------------------
__global__ __launch_bounds__(256, 2)
void k4_out(const unsigned short* __restrict__ u, const unsigned short* __restrict__ W2,
            const float* __restrict__ ego, float* __restrict__ out) {
  __shared__ __align__(16) unsigned short Au[32 * 256];  // 16KB, swizzled
  const int tid = threadIdx.x;
  const int bM = blockIdx.x * 32;
  const int w = tid >> 6, lane = tid & 63, lr = lane & 15, lkg = lane >> 4;
  f32x4 acc[2][4];
#pragma unroll
  for (int mt = 0; mt < 2; ++mt)
#pragma unroll
    for (int nt = 0; nt < 4; ++nt) acc[mt][nt] = (f32x4){0.f, 0.f, 0.f, 0.f};
#pragma unroll 1
  for (int kc = 0; kc < 5; ++kc) {
#pragma unroll
    for (int it = 0; it < 4; ++it) {
      int c = tid + it * 256;              // 1024 chunks of 8 bf16
      int row = c >> 5, k8 = c & 31;
      bf16x8 v = *(const bf16x8*)(u + (size_t)(bM + row) * 1280 + kc * 256 + k8 * 8);
      int byteoff = row * 512 + ((k8 * 16) ^ ((row & 7) << 4));
      *(bf16x8*)((char*)Au + byteoff) = v;
    }
    __syncthreads();
#pragma unroll
    for (int kk = 0; kk < 8; ++kk) {
      int kidx = kk * 32 + lkg * 8;
      bf16x8 bfr[4];
#pragma unroll
      for (int nt = 0; nt < 4; ++nt)
        bfr[nt] = *(const bf16x8*)(W2 + (size_t)(w * 64 + nt * 16 + lr) * 1280 + kc * 256 + kidx);
#pragma unroll
      for (int mt = 0; mt < 2; ++mt) {
        int row = mt * 16 + lr;
        int byteoff = row * 512 + ((kidx * 2) ^ ((row & 7) << 4));
        bf16x8 a = *(const bf16x8*)((const char*)Au + byteoff);
#pragma unroll
        for (int nt = 0; nt < 4; ++nt)
          acc[mt][nt] = __builtin_amdgcn_mfma_f32_16x16x32_bf16(a, bfr[nt], acc[mt][nt], 0, 0, 0);
      }
    }
    __syncthreads();
  }
#pragma unroll
  for (int mt = 0; mt < 2; ++mt)
#pragma unroll
    for (int nt = 0; nt < 4; ++nt)
#pragma unroll
      for (int j = 0; j < 4; ++j) {
        int row = bM + mt * 16 + lkg * 4 + j;
        int col = w * 64 + nt * 16 + lr;
        out[(size_t)row * 256 + col] = (acc[mt][nt][j] + ego[(size_t)row * 256 + col]) * 0.5f;
      }
}

extern "C" void kernel_launch(void* const* d_in, const int* in_sizes, int n_in,
                              void* d_out, int out_size, void* d_ws, size_t ws_size,
                              hipStream_t stream) {
  const float* ego    = (const float*)d_in[0];
  const float* others = (const float*)d_in[1];
  const int*   mask   = (const int*)d_in[2];
  const float* wq  = (const float*)d_in[3];
  const float* wk  = (const float*)d_in[4];
  const float* wv  = (const float*)d_in[5];
  const float* wok = (const float*)d_in[6];
  const float* wov = (const float*)d_in[7];
  const float* wc  = (const float*)d_in[8];

  unsigned short* W1   = (unsigned short*)d_ws;                 // 1792*256
  unsigned short* W2   = W1 + 1792 * 256;                       // 256*1280
  unsigned short* qkv2 = W2 + 256 * 1280;                       // NB*1792
  unsigned short* u    = qkv2 + (size_t)NB * 1792;              // NB*1280

  float* res  = (float*)d_out;                                  // NB*256 f32
  float* attn = res + (size_t)NB * 256;                         // NB*128 f32

  // DIAGNOSTIC ROUND: all kernels are pure/idempotent. Multiplicities
  // {k0,k1b,k4}x3, ks x2 let us solve per-kernel times from two totals:
  //   R + K = T_round10 (~230),  3R + 2K = T_this  =>  R = T_this - 460.
  for (int rep = 0; rep < 3; ++rep)
    hipLaunchKernelGGL(k0_all, dim3(2304), dim3(256), 0, stream,
                       wq, wk, wv, wok, wov, wc, W1, W2);
  for (int rep = 0; rep < 3; ++rep)
    hipLaunchKernelGGL(k1b,    dim3(512),  dim3(256), 0, stream, ego, W1, qkv2);
  for (int rep = 0; rep < 2; ++rep)
    hipLaunchKernelGGL(ks_attn, dim3(NB), dim3(64), 0, stream,
                       others, mask, qkv2, u, attn);
  for (int rep = 0; rep < 3; ++rep)
    hipLaunchKernelGGL(k4_out, dim3(512),  dim3(256), 0, stream, u, W2, ego, res);
}

// Round 14
// 257.833 us; speedup vs baseline: 2.0623x; 2.0623x over previous
//
#include <hip/hip_runtime.h>
#include <hip/hip_bf16.h>

typedef __attribute__((ext_vector_type(8))) short bf16x8;
typedef __attribute__((ext_vector_type(4))) float f32x4;

#define NB 16384
#define NE 31

static __device__ __forceinline__ unsigned short f2b(float f) {
  unsigned int u = __builtin_bit_cast(unsigned int, f);
  return (unsigned short)((u + 0x7fffu + ((u >> 16) & 1u)) >> 16);
}
static __device__ __forceinline__ float b2f(unsigned short h) {
  return __builtin_bit_cast(float, ((unsigned int)h) << 16);
}
static __device__ __forceinline__ unsigned int cvtpk(float a, float b) {
  unsigned int r;
  asm("v_cvt_pk_bf16_f32 %0, %1, %2" : "=v"(r) : "v"(a), "v"(b));
  return r;
}
static __device__ __forceinline__ bf16x8 pack8(float4 x, float4 y) {
  int4 t;
  t.x = (int)cvtpk(x.x, x.y);
  t.y = (int)cvtpk(x.z, x.w);
  t.z = (int)cvtpk(y.x, y.y);
  t.w = (int)cvtpk(y.z, y.w);
  return __builtin_bit_cast(bf16x8, t);
}

// ---------------------------------------------------------------------------
// k0_all: weight preprocessing (one launch). Layouts as before.
// ---------------------------------------------------------------------------
__global__ void k0_all(const float* __restrict__ wq, const float* __restrict__ wk,
                       const float* __restrict__ wv, const float* __restrict__ wok,
                       const float* __restrict__ wov, const float* __restrict__ wc,
                       unsigned short* __restrict__ W1, unsigned short* __restrict__ W2) {
  int r = blockIdx.x, k = threadIdx.x;
  if (r < 1024) {
    if (r < 256) {
      W1[r * 256 + k] = f2b(0.125f * wq[r * 256 + k]);
    } else if (r < 512) {
      W1[r * 256 + k] = f2b(wk[(r - 256) * 256 + k]);
    } else if (r < 768) {
      W1[r * 256 + k] = f2b(wv[(r - 512) * 256 + k]);
    } else {
      int n = r - 768;
      W2[n * 1280 + 1024 + k] = f2b(wc[n * 256 + k]);
    }
  } else if (r < 2048) {
    int m = r - 1024;  // 0..1023
    int h = m >> 8, c = m & 255;
    float acc = 0.f;
#pragma unroll 8
    for (int d = 0; d < 64; ++d)
      acc = fmaf(wq[(h * 64 + d) * 256 + k], wok[(h * 64 + d) * 256 + c], acc);
    W1[(768 + m) * 256 + k] = f2b(0.125f * acc);
  } else {
    int n = r - 2048;  // 0..255
#pragma unroll 1
    for (int mi = 0; mi < 4; ++mi) {
      float acc = 0.f;
#pragma unroll 8
      for (int d = 0; d < 64; ++d)
        acc = fmaf(wov[(mi * 64 + d) * 256 + k], wc[n * 256 + mi * 64 + d], acc);
      W2[n * 1280 + mi * 256 + k] = f2b(acc);
    }
  }
}

// ---------------------------------------------------------------------------
// k1b: qkv2[b][n] = sum_k ego[b][k] * W1[n][k]. bf16 out.
// 512 blocks: (row-group 64) x (col-half 896). NO LDS, NO barriers:
// A-fragments loaded direct from global (bf16-converted, hoisted in regs).
// ---------------------------------------------------------------------------
__global__ __launch_bounds__(256, 2)
void k1b(const float* __restrict__ ego, const unsigned short* __restrict__ W1,
         unsigned short* __restrict__ qkv2) {
  const int tid = threadIdx.x;
  const int bM = (blockIdx.x >> 1) * 64;
  const int half = (blockIdx.x & 1) * 896;
  const int w = tid >> 6, lane = tid & 63, lr = lane & 15, lkg = lane >> 4;

  // A-frags direct: af[mt][kk] = bf16(ego[bM+mt*16+lr][kk*32+lkg*8 .. +8])
  bf16x8 af[4][8];
#pragma unroll
  for (int mt = 0; mt < 4; ++mt) {
    const float* rowp = ego + (size_t)(bM + mt * 16 + lr) * 256 + lkg * 8;
#pragma unroll
    for (int kk = 0; kk < 8; ++kk) {
      float4 x = *(const float4*)(rowp + kk * 32);
      float4 y = *(const float4*)(rowp + kk * 32 + 4);
      af[mt][kk] = pack8(x, y);
    }
  }

#pragma unroll 1
  for (int cb = 0; cb < 7; ++cb) {
    int bN = half + w * 224 + cb * 32;
    f32x4 acc[4][2];
#pragma unroll
    for (int mt = 0; mt < 4; ++mt)
#pragma unroll
      for (int nt = 0; nt < 2; ++nt) acc[mt][nt] = (f32x4){0.f, 0.f, 0.f, 0.f};
#pragma unroll
    for (int kk = 0; kk < 8; ++kk) {
      int kidx = kk * 32 + lkg * 8;
      bf16x8 bfr[2];
#pragma unroll
      for (int nt = 0; nt < 2; ++nt)
        bfr[nt] = *(const bf16x8*)(W1 + (size_t)(bN + nt * 16 + lr) * 256 + kidx);
#pragma unroll
      for (int mt = 0; mt < 4; ++mt)
#pragma unroll
        for (int nt = 0; nt < 2; ++nt)
          acc[mt][nt] = __builtin_amdgcn_mfma_f32_16x16x32_bf16(af[mt][kk], bfr[nt], acc[mt][nt], 0, 0, 0);
    }
#pragma unroll
    for (int mt = 0; mt < 4; ++mt)
#pragma unroll
      for (int nt = 0; nt < 2; ++nt)
#pragma unroll
        for (int j = 0; j < 4; ++j) {
          int row = bM + mt * 16 + lkg * 4 + j;
          int col = bN + nt * 16 + lr;
          qkv2[(size_t)row * 1792 + col] = f2b(acc[mt][nt][j]);
        }
  }
}

// ---------------------------------------------------------------------------
// ks_attn: ONE 64-THREAD BLOCK = ONE ITEM (round-10 version).
// (64,2): VGPR cap 256 -> full 31-load stage burst stays in flight.
// ---------------------------------------------------------------------------
__global__ __launch_bounds__(64, 2)
void ks_attn(const float* __restrict__ others, const int* __restrict__ mask,
             const unsigned short* __restrict__ qkv2,
             unsigned short* __restrict__ u,
             float* __restrict__ attnout) {
  __shared__ __align__(16) unsigned short Xs[8192];  // exactly 16KB
  const int lane = threadIdx.x;                      // 0..63
  const int lr = lane & 15, lkg = lane >> 4;
  const size_t b = blockIdx.x;
  char* Xc = (char*)Xs;
  const unsigned short* qk = qkv2 + b * 1792;

  bf16x8 af[8];
#pragma unroll
  for (int kk = 0; kk < 8; ++kk)
    af[kk] = *(const bf16x8*)(qk + 768 + (lr & 3) * 256 + kk * 32 + lkg * 8);
  ushort4 qa = *(const ushort4*)(qk + lkg * 64 + lr * 4);
  ushort4 kb = *(const ushort4*)(qk + 256 + lkg * 64 + lr * 4);
  ushort4 ve = *(const ushort4*)(qk + 512 + lane * 4);
  int mk0 = mask[b * 32 + 1 + lr];
  int mk1 = (lr == 15) ? 1 : mask[b * 32 + 17 + lr];
  int mkE = mask[b * 32];

  {
    const char* src = (const char*)(others + b * (NE * 256)) + lane * 16;
#pragma unroll
    for (int j = 0; j < NE; ++j) {
      float4 f = *(const float4*)(src + j * 1024);
      uint2 v;
      v.x = cvtpk(f.x, f.y);
      v.y = cvtpk(f.z, f.w);
      *(uint2*)(Xc + j * 512 + ((lane * 8) ^ ((j & 15) << 4))) = v;
    }
    uint2 z; z.x = 0; z.y = 0;
    *(uint2*)(Xc + 31 * 512 + ((lane * 8) ^ ((31 & 15) << 4))) = z;
  }

  float s0p = b2f(qa.x) * b2f(kb.x) + b2f(qa.y) * b2f(kb.y) +
              b2f(qa.z) * b2f(kb.z) + b2f(qa.w) * b2f(kb.w);
#pragma unroll
  for (int off = 1; off < 16; off <<= 1) s0p += __shfl_xor(s0p, off, 16);
  float s0h[4];
  s0h[0] = __shfl(s0p, 0);
  s0h[1] = __shfl(s0p, 16);
  s0h[2] = __shfl(s0p, 32);
  s0h[3] = __shfl(s0p, 48);

  asm volatile("s_waitcnt lgkmcnt(0)" ::: "memory");
  __builtin_amdgcn_sched_barrier(0);

  f32x4 acc0 = (f32x4){0.f, 0.f, 0.f, 0.f};
  f32x4 acc1 = (f32x4){0.f, 0.f, 0.f, 0.f};
#pragma unroll
  for (int kk = 0; kk < 8; ++kk) {
    int co = kk * 64 + lkg * 16;
    bf16x8 b0 = *(const bf16x8*)(Xc + lr * 512 + (co ^ (lr << 4)));
    bf16x8 b1 = *(const bf16x8*)(Xc + (16 + lr) * 512 + (co ^ (lr << 4)));
    acc0 = __builtin_amdgcn_mfma_f32_16x16x32_bf16(af[kk], b0, acc0, 0, 0, 0);
    acc1 = __builtin_amdgcn_mfma_f32_16x16x32_bf16(af[kk], b1, acc1, 0, 0, 0);
  }

  float pr0[4], pr1[4], p0v[4];
#pragma unroll
  for (int j = 0; j < 4; ++j) {
    float sj0 = mk0 ? -1e9f : acc0[j];
    float sj1 = mk1 ? -1e9f : acc1[j];
    float se  = mkE ? -1e9f : s0h[j];
    float mx = fmaxf(se, fmaxf(sj0, sj1));
#pragma unroll
    for (int off = 1; off < 16; off <<= 1) mx = fmaxf(mx, __shfl_xor(mx, off, 16));
    float e0 = __expf(sj0 - mx), e1 = __expf(sj1 - mx), ee = __expf(se - mx);
    float sm = e0 + e1;
#pragma unroll
    for (int off = 1; off < 16; off <<= 1) sm += __shfl_xor(sm, off, 16);
    float rinv = 1.f / (sm + ee);
    pr0[j] = e0 * rinv;
    pr1[j] = e1 * rinv;
    p0v[j] = ee * rinv;
  }
  if (lkg == 0) {
#pragma unroll
    for (int j = 0; j < 4; ++j) {
      attnout[b * 128 + j * 32 + 1 + lr] = pr0[j];
      if (lr < 15) attnout[b * 128 + j * 32 + 17 + lr] = pr1[j];
      if (lr == 0) attnout[b * 128 + j * 32] = p0v[j];
    }
  }

  f32x4 cx[4];
#pragma unroll
  for (int h = 0; h < 4; ++h) cx[h] = (f32x4){0.f, 0.f, 0.f, 0.f};
#pragma unroll
  for (int e = 0; e < NE; ++e) {
    float p0, p1, p2, p3;
    if (e < 16) {
      p0 = __shfl(pr0[0], e); p1 = __shfl(pr0[1], e);
      p2 = __shfl(pr0[2], e); p3 = __shfl(pr0[3], e);
    } else {
      p0 = __shfl(pr1[0], e - 16); p1 = __shfl(pr1[1], e - 16);
      p2 = __shfl(pr1[2], e - 16); p3 = __shfl(pr1[3], e - 16);
    }
    ushort4 xr = *(const ushort4*)(Xc + e * 512 + ((lane * 8) ^ ((e & 15) << 4)));
    float x0 = b2f(xr.x), x1 = b2f(xr.y), x2 = b2f(xr.z), x3 = b2f(xr.w);
    cx[0][0] = fmaf(p0, x0, cx[0][0]); cx[0][1] = fmaf(p0, x1, cx[0][1]);
    cx[0][2] = fmaf(p0, x2, cx[0][2]); cx[0][3] = fmaf(p0, x3, cx[0][3]);
    cx[1][0] = fmaf(p1, x0, cx[1][0]); cx[1][1] = fmaf(p1, x1, cx[1][1]);
    cx[1][2] = fmaf(p1, x2, cx[1][2]); cx[1][3] = fmaf(p1, x3, cx[1][3]);
    cx[2][0] = fmaf(p2, x0, cx[2][0]); cx[2][1] = fmaf(p2, x1, cx[2][1]);
    cx[2][2] = fmaf(p2, x2, cx[2][2]); cx[2][3] = fmaf(p2, x3, cx[2][3]);
    cx[3][0] = fmaf(p3, x0, cx[3][0]); cx[3][1] = fmaf(p3, x1, cx[3][1]);
    cx[3][2] = fmaf(p3, x2, cx[3][2]); cx[3][3] = fmaf(p3, x3, cx[3][3]);
  }
#pragma unroll
  for (int h = 0; h < 4; ++h) {
    ushort4 st;
    st.x = f2b(cx[h][0]); st.y = f2b(cx[h][1]);
    st.z = f2b(cx[h][2]); st.w = f2b(cx[h][3]);
    *(ushort4*)(u + b * 1280 + h * 256 + lane * 4) = st;
  }
  {
    float p0h = (lkg == 0) ? p0v[0] : (lkg == 1) ? p0v[1] : (lkg == 2) ? p0v[2] : p0v[3];
    ushort4 sv;
    sv.x = f2b(p0h * b2f(ve.x)); sv.y = f2b(p0h * b2f(ve.y));
    sv.z = f2b(p0h * b2f(ve.z)); sv.w = f2b(p0h * b2f(ve.w));
    *(ushort4*)(u + b * 1280 + 1024 + lane * 4) = sv;
  }
}

// ---------------------------------------------------------------------------
// k4: res[b][n] = (sum_m u[b][m]*W2[n][m] + ego[b][n]) * 0.5
// 512 blocks x 32 rows. NO LDS, NO barriers: A-frags direct from u (bf16).
// ---------------------------------------------------------------------------
__global__ __launch_bounds__(256, 2)
void k4_out(const unsigned short* __restrict__ u, const unsigned short* __restrict__ W2,
            const float* __restrict__ ego, float* __restrict__ out) {
  const int tid = threadIdx.x;
  const int bM = blockIdx.x * 32;
  const int w = tid >> 6, lane = tid & 63, lr = lane & 15, lkg = lane >> 4;
  f32x4 acc[2][4];
#pragma unroll
  for (int mt = 0; mt < 2; ++mt)
#pragma unroll
    for (int nt = 0; nt < 4; ++nt) acc[mt][nt] = (f32x4){0.f, 0.f, 0.f, 0.f};
#pragma unroll 1
  for (int kc = 0; kc < 5; ++kc) {
#pragma unroll
    for (int kk = 0; kk < 8; ++kk) {
      int kidx = kc * 256 + kk * 32 + lkg * 8;
      bf16x8 a[2], bfr[4];
#pragma unroll
      for (int mt = 0; mt < 2; ++mt)
        a[mt] = *(const bf16x8*)(u + (size_t)(bM + mt * 16 + lr) * 1280 + kidx);
#pragma unroll
      for (int nt = 0; nt < 4; ++nt)
        bfr[nt] = *(const bf16x8*)(W2 + (size_t)(w * 64 + nt * 16 + lr) * 1280 + kidx);
#pragma unroll
      for (int mt = 0; mt < 2; ++mt)
#pragma unroll
        for (int nt = 0; nt < 4; ++nt)
          acc[mt][nt] = __builtin_amdgcn_mfma_f32_16x16x32_bf16(a[mt], bfr[nt], acc[mt][nt], 0, 0, 0);
    }
  }
#pragma unroll
  for (int mt = 0; mt < 2; ++mt)
#pragma unroll
    for (int nt = 0; nt < 4; ++nt)
#pragma unroll
      for (int j = 0; j < 4; ++j) {
        int row = bM + mt * 16 + lkg * 4 + j;
        int col = w * 64 + nt * 16 + lr;
        out[(size_t)row * 256 + col] = (acc[mt][nt][j] + ego[(size_t)row * 256 + col]) * 0.5f;
      }
}

extern "C" void kernel_launch(void* const* d_in, const int* in_sizes, int n_in,
                              void* d_out, int out_size, void* d_ws, size_t ws_size,
                              hipStream_t stream) {
  const float* ego    = (const float*)d_in[0];
  const float* others = (const float*)d_in[1];
  const int*   mask   = (const int*)d_in[2];
  const float* wq  = (const float*)d_in[3];
  const float* wk  = (const float*)d_in[4];
  const float* wv  = (const float*)d_in[5];
  const float* wok = (const float*)d_in[6];
  const float* wov = (const float*)d_in[7];
  const float* wc  = (const float*)d_in[8];

  unsigned short* W1   = (unsigned short*)d_ws;                 // 1792*256
  unsigned short* W2   = W1 + 1792 * 256;                       // 256*1280
  unsigned short* qkv2 = W2 + 256 * 1280;                       // NB*1792
  unsigned short* u    = qkv2 + (size_t)NB * 1792;              // NB*1280

  float* res  = (float*)d_out;                                  // NB*256 f32
  float* attn = res + (size_t)NB * 256;                         // NB*128 f32

  hipLaunchKernelGGL(k0_all, dim3(2304), dim3(256), 0, stream,
                     wq, wk, wv, wok, wov, wc, W1, W2);
  hipLaunchKernelGGL(k1b,    dim3(512),  dim3(256), 0, stream, ego, W1, qkv2);
  hipLaunchKernelGGL(ks_attn, dim3(NB), dim3(64), 0, stream,
                     others, mask, qkv2, u, attn);
  hipLaunchKernelGGL(k4_out, dim3(512),  dim3(256), 0, stream, u, W2, ego, res);
}

// Round 15
// 227.338 us; speedup vs baseline: 2.3390x; 1.1341x over previous
//
#include <hip/hip_runtime.h>
#include <hip/hip_bf16.h>

typedef __attribute__((ext_vector_type(8))) short bf16x8;
typedef __attribute__((ext_vector_type(4))) float f32x4;

#define NB 16384
#define NE 31

static __device__ __forceinline__ unsigned short f2b(float f) {
  unsigned int u = __builtin_bit_cast(unsigned int, f);
  return (unsigned short)((u + 0x7fffu + ((u >> 16) & 1u)) >> 16);
}
static __device__ __forceinline__ float b2f(unsigned short h) {
  return __builtin_bit_cast(float, ((unsigned int)h) << 16);
}
static __device__ __forceinline__ unsigned int cvtpk(float a, float b) {
  unsigned int r;
  asm("v_cvt_pk_bf16_f32 %0, %1, %2" : "=v"(r) : "v"(a), "v"(b));
  return r;
}
static __device__ __forceinline__ float lo16(unsigned int v) {
  return __builtin_bit_cast(float, v << 16);
}
static __device__ __forceinline__ float hi16(unsigned int v) {
  return __builtin_bit_cast(float, v & 0xffff0000u);
}

// ---------------------------------------------------------------------------
// k0_all: weight preprocessing (one launch).
// W1 (bf16 [1792][256]): rows 0..255 = 0.125*Wq; 256..511 = Wk; 512..767 = Wv;
//   rows 768..1791 = Wqo[h*256+c][k] = sum_d 0.125*Wq[h*64+d][k]*Wok[h*64+d][c]
// W2 (bf16 [256][1280]): row n: cols h*256+c = sum_d Wov[h*64+d][c]*Wc[n][h*64+d];
//   cols 1024+m = Wc[n][m]
// ---------------------------------------------------------------------------
__global__ void k0_all(const float* __restrict__ wq, const float* __restrict__ wk,
                       const float* __restrict__ wv, const float* __restrict__ wok,
                       const float* __restrict__ wov, const float* __restrict__ wc,
                       unsigned short* __restrict__ W1, unsigned short* __restrict__ W2) {
  int r = blockIdx.x, k = threadIdx.x;
  if (r < 1024) {
    if (r < 256) {
      W1[r * 256 + k] = f2b(0.125f * wq[r * 256 + k]);
    } else if (r < 512) {
      W1[r * 256 + k] = f2b(wk[(r - 256) * 256 + k]);
    } else if (r < 768) {
      W1[r * 256 + k] = f2b(wv[(r - 512) * 256 + k]);
    } else {
      int n = r - 768;
      W2[n * 1280 + 1024 + k] = f2b(wc[n * 256 + k]);
    }
  } else if (r < 2048) {
    int m = r - 1024;  // 0..1023
    int h = m >> 8, c = m & 255;
    float acc = 0.f;
#pragma unroll 8
    for (int d = 0; d < 64; ++d)
      acc = fmaf(wq[(h * 64 + d) * 256 + k], wok[(h * 64 + d) * 256 + c], acc);
    W1[(768 + m) * 256 + k] = f2b(0.125f * acc);
  } else {
    int n = r - 2048;  // 0..255
#pragma unroll 1
    for (int mi = 0; mi < 4; ++mi) {
      float acc = 0.f;
#pragma unroll 8
      for (int d = 0; d < 64; ++d)
        acc = fmaf(wov[(mi * 64 + d) * 256 + k], wc[n * 256 + mi * 64 + d], acc);
      W2[n * 1280 + mi * 256 + k] = f2b(acc);
    }
  }
}

// ---------------------------------------------------------------------------
// k1b: qkv2[b][n] = sum_k ego[b][k] * W1[n][k]. bf16 out.
// 512 blocks: (row-group 64) x (col-half 896); 2 blocks/CU.
// LDS-staged A (coalesced stage -> swizzled reads). Round-7 champion shape.
// ---------------------------------------------------------------------------
__global__ __launch_bounds__(256, 2)
void k1b(const float* __restrict__ ego, const unsigned short* __restrict__ W1,
         unsigned short* __restrict__ qkv2) {
  __shared__ __align__(16) unsigned short Al[64 * 256];  // 32KB, swizzled
  const int tid = threadIdx.x;
  const int bM = (blockIdx.x >> 1) * 64;
  const int half = (blockIdx.x & 1) * 896;
#pragma unroll
  for (int it = 0; it < 8; ++it) {
    int c = tid + it * 256;                // 2048 chunks of 8 f32
    int row = c >> 5, k8 = c & 31;
    const float4* g = (const float4*)(ego + (size_t)(bM + row) * 256 + k8 * 8);
    float4 x = g[0], y = g[1];
    float t[8] = {x.x, x.y, x.z, x.w, y.x, y.y, y.z, y.w};
    bf16x8 v;
#pragma unroll
    for (int j = 0; j < 8; ++j) v[j] = (short)f2b(t[j]);
    int byteoff = row * 512 + ((k8 * 16) ^ ((row & 7) << 4));
    *(bf16x8*)((char*)Al + byteoff) = v;
  }
  __syncthreads();
  const int w = tid >> 6, lane = tid & 63, lr = lane & 15, lkg = lane >> 4;
#pragma unroll 1
  for (int cb = 0; cb < 7; ++cb) {
    int bN = half + w * 224 + cb * 32;
    f32x4 acc[4][2];
#pragma unroll
    for (int mt = 0; mt < 4; ++mt)
#pragma unroll
      for (int nt = 0; nt < 2; ++nt) acc[mt][nt] = (f32x4){0.f, 0.f, 0.f, 0.f};
#pragma unroll
    for (int kk = 0; kk < 8; ++kk) {
      int kidx = kk * 32 + lkg * 8;
      bf16x8 bfr[2];
#pragma unroll
      for (int nt = 0; nt < 2; ++nt)
        bfr[nt] = *(const bf16x8*)(W1 + (size_t)(bN + nt * 16 + lr) * 256 + kidx);
#pragma unroll
      for (int mt = 0; mt < 4; ++mt) {
        int row = mt * 16 + lr;
        int byteoff = row * 512 + ((kidx * 2) ^ ((row & 7) << 4));
        bf16x8 a = *(const bf16x8*)((const char*)Al + byteoff);
#pragma unroll
        for (int nt = 0; nt < 2; ++nt)
          acc[mt][nt] = __builtin_amdgcn_mfma_f32_16x16x32_bf16(a, bfr[nt], acc[mt][nt], 0, 0, 0);
      }
    }
#pragma unroll
    for (int mt = 0; mt < 4; ++mt)
#pragma unroll
      for (int nt = 0; nt < 2; ++nt)
#pragma unroll
        for (int j = 0; j < 4; ++j) {
          int row = bM + mt * 16 + lkg * 4 + j;
          int col = bN + nt * 16 + lr;
          qkv2[(size_t)row * 1792 + col] = f2b(acc[mt][nt][j]);
        }
  }
}

// ---------------------------------------------------------------------------
// ks_attn: ONE WAVE = ONE ITEM, zero barriers (round-7 champion). 4 waves per
// 256-thread block, private LDS slices. Stage X bf16 (swizzled LDS for the
// score MFMAs + packed regs for ctx), MFMA scores, in-wave softmax, ctx from
// REGISTERS. grid = NB/4.
// ---------------------------------------------------------------------------
__global__ __launch_bounds__(256, 2)
void ks_attn(const float* __restrict__ others, const int* __restrict__ mask,
             const unsigned short* __restrict__ qkv2,
             unsigned short* __restrict__ u,
             float* __restrict__ attnout) {
  __shared__ __align__(16) unsigned short Xs[4][8192];  // 16KB per wave
  __shared__ __align__(16) float Ps[4][32][4];          // [key][head] per wave
  const int tid = threadIdx.x;
  const int w = tid >> 6, lane = tid & 63, lr = lane & 15, lkg = lane >> 4;
  const size_t b = (size_t)blockIdx.x * 4 + w;
  char* Xc = (char*)Xs[w];
  float (*P)[4] = Ps[w];
  const unsigned short* qk = qkv2 + b * 1792;

  // ---- preload A-fragments (Qo) + ego q/k/v bits (L2-resident) ----
  bf16x8 af[8];
#pragma unroll
  for (int kk = 0; kk < 8; ++kk)
    af[kk] = *(const bf16x8*)(qk + 768 + (lr & 3) * 256 + kk * 32 + lkg * 8);
  ushort4 qa = *(const ushort4*)(qk + lkg * 64 + lr * 4);
  ushort4 kb = *(const ushort4*)(qk + 256 + lkg * 64 + lr * 4);
  ushort4 ve = *(const ushort4*)(qk + 512 + lane * 4);
  int mk0 = mask[b * 32 + 1 + lr];
  int mk1 = (lr == 15) ? 1 : mask[b * 32 + 17 + lr];
  int mkE = mask[b * 32];

  // ---- stage X: row j, f32-chunk `lane` (coalesced 1KB/inst).
  //      Keep packed copy xv[j] in regs: lane owns cols 4*lane..4*lane+3. ----
  uint2 xv[NE];
  {
    const char* src = (const char*)(others + b * (NE * 256)) + lane * 16;
#pragma unroll
    for (int j = 0; j < NE; ++j) {
      float4 f = *(const float4*)(src + j * 1024);
      uint2 v;
      v.x = cvtpk(f.x, f.y);
      v.y = cvtpk(f.z, f.w);
      xv[j] = v;
      *(uint2*)(Xc + j * 512 + ((lane * 8) ^ ((j & 15) << 4))) = v;
    }
    uint2 z; z.x = 0; z.y = 0;
    *(uint2*)(Xc + 31 * 512 + ((lane * 8) ^ ((31 & 15) << 4))) = z;
  }

  // ---- s0[h] = q_h . k_ego_h (q pre-scaled); group lkg computes head lkg ----
  float s0p = b2f(qa.x) * b2f(kb.x) + b2f(qa.y) * b2f(kb.y) +
              b2f(qa.z) * b2f(kb.z) + b2f(qa.w) * b2f(kb.w);
#pragma unroll
  for (int off = 1; off < 16; off <<= 1) s0p += __shfl_xor(s0p, off, 16);
  float s0h[4];
  s0h[0] = __shfl(s0p, 0);
  s0h[1] = __shfl(s0p, 16);
  s0h[2] = __shfl(s0p, 32);
  s0h[3] = __shfl(s0p, 48);

  asm volatile("s_waitcnt lgkmcnt(0)" ::: "memory");
  __builtin_amdgcn_sched_barrier(0);

  // ---- scores: S[h][e] via MFMA; D row m=h (valid on lkg==0), col n=e ----
  f32x4 acc0 = (f32x4){0.f, 0.f, 0.f, 0.f};
  f32x4 acc1 = (f32x4){0.f, 0.f, 0.f, 0.f};
#pragma unroll
  for (int kk = 0; kk < 8; ++kk) {
    int co = kk * 64 + lkg * 16;
    bf16x8 b0 = *(const bf16x8*)(Xc + lr * 512 + (co ^ (lr << 4)));
    bf16x8 b1 = *(const bf16x8*)(Xc + (16 + lr) * 512 + (co ^ (lr << 4)));
    acc0 = __builtin_amdgcn_mfma_f32_16x16x32_bf16(af[kk], b0, acc0, 0, 0, 0);
    acc1 = __builtin_amdgcn_mfma_f32_16x16x32_bf16(af[kk], b1, acc1, 0, 0, 0);
  }

  // ---- masked softmax per head (width-16 shfl groups; lkg==0 valid) ----
  float pr0[4], pr1[4], p0v[4];
#pragma unroll
  for (int j = 0; j < 4; ++j) {
    float sj0 = mk0 ? -1e9f : acc0[j];
    float sj1 = mk1 ? -1e9f : acc1[j];
    float se  = mkE ? -1e9f : s0h[j];
    float mx = fmaxf(se, fmaxf(sj0, sj1));
#pragma unroll
    for (int off = 1; off < 16; off <<= 1) mx = fmaxf(mx, __shfl_xor(mx, off, 16));
    float e0 = __expf(sj0 - mx), e1 = __expf(sj1 - mx), ee = __expf(se - mx);
    float sm = e0 + e1;
#pragma unroll
    for (int off = 1; off < 16; off <<= 1) sm += __shfl_xor(sm, off, 16);
    float rinv = 1.f / (sm + ee);
    pr0[j] = e0 * rinv;
    pr1[j] = e1 * rinv;
    p0v[j] = ee * rinv;
  }
  if (lkg == 0) {
    float4 q0, q1;
    q0.x = pr0[0]; q0.y = pr0[1]; q0.z = pr0[2]; q0.w = pr0[3];
    *(float4*)&P[1 + lr][0] = q0;
    if (lr < 15) {
      q1.x = pr1[0]; q1.y = pr1[1]; q1.z = pr1[2]; q1.w = pr1[3];
      *(float4*)&P[17 + lr][0] = q1;
    }
    if (lr == 0) {
      float4 qe;
      qe.x = p0v[0]; qe.y = p0v[1]; qe.z = p0v[2]; qe.w = p0v[3];
      *(float4*)&P[0][0] = qe;
    }
#pragma unroll
    for (int j = 0; j < 4; ++j) {
      attnout[b * 128 + j * 32 + 1 + lr] = pr0[j];
      if (lr < 15) attnout[b * 128 + j * 32 + 17 + lr] = pr1[j];
      if (lr == 0) attnout[b * 128 + j * 32] = p0v[j];
    }
  }
  asm volatile("s_waitcnt lgkmcnt(0)" ::: "memory");
  __builtin_amdgcn_sched_barrier(0);

  // ---- ctx[h][d] = sum_e P[h][e] X[e][d]; lane owns 4 d-cols (from regs) ----
  f32x4 cx[4];
#pragma unroll
  for (int h = 0; h < 4; ++h) cx[h] = (f32x4){0.f, 0.f, 0.f, 0.f};
#pragma unroll
  for (int e = 0; e < NE; ++e) {
    float4 p = *(const float4*)&P[1 + e][0];
    uint2 v = xv[e];
    float x0 = lo16(v.x), x1 = hi16(v.x), x2 = lo16(v.y), x3 = hi16(v.y);
    cx[0][0] = fmaf(p.x, x0, cx[0][0]); cx[0][1] = fmaf(p.x, x1, cx[0][1]);
    cx[0][2] = fmaf(p.x, x2, cx[0][2]); cx[0][3] = fmaf(p.x, x3, cx[0][3]);
    cx[1][0] = fmaf(p.y, x0, cx[1][0]); cx[1][1] = fmaf(p.y, x1, cx[1][1]);
    cx[1][2] = fmaf(p.y, x2, cx[1][2]); cx[1][3] = fmaf(p.y, x3, cx[1][3]);
    cx[2][0] = fmaf(p.z, x0, cx[2][0]); cx[2][1] = fmaf(p.z, x1, cx[2][1]);
    cx[2][2] = fmaf(p.z, x2, cx[2][2]); cx[2][3] = fmaf(p.z, x3, cx[2][3]);
    cx[3][0] = fmaf(p.w, x0, cx[3][0]); cx[3][1] = fmaf(p.w, x1, cx[3][1]);
    cx[3][2] = fmaf(p.w, x2, cx[3][2]); cx[3][3] = fmaf(p.w, x3, cx[3][3]);
  }
#pragma unroll
  for (int h = 0; h < 4; ++h) {
    ushort4 st;
    st.x = f2b(cx[h][0]); st.y = f2b(cx[h][1]);
    st.z = f2b(cx[h][2]); st.w = f2b(cx[h][3]);
    *(ushort4*)(u + b * 1280 + h * 256 + lane * 4) = st;
  }
  // p0 * v_ego (head = lkg for this lane's 4-col slice)
  float p0h = P[0][lkg];
  ushort4 sv;
  sv.x = f2b(p0h * b2f(ve.x)); sv.y = f2b(p0h * b2f(ve.y));
  sv.z = f2b(p0h * b2f(ve.z)); sv.w = f2b(p0h * b2f(ve.w));
  *(ushort4*)(u + b * 1280 + 1024 + lane * 4) = sv;
}

// ---------------------------------------------------------------------------
// k4: res[b][n] = (sum_m u[b][m]*W2[n][m] + ego[b][n]) * 0.5  (round-7 shape)
// 512 blocks x 32 rows; K looped in 5 chunks of 256; 4 waves = 64-col stripes.
// ---------------------------------------------------------------------------
__global__ __launch_bounds__(256, 2)
void k4_out(const unsigned short* __restrict__ u, const unsigned short* __restrict__ W2,
            const float* __restrict__ ego, float* __restrict__ out) {
  __shared__ __align__(16) unsigned short Au[32 * 256];  // 16KB, swizzled
  const int tid = threadIdx.x;
  const int bM = blockIdx.x * 32;
  const int w = tid >> 6, lane = tid & 63, lr = lane & 15, lkg = lane >> 4;
  f32x4 acc[2][4];
#pragma unroll
  for (int mt = 0; mt < 2; ++mt)
#pragma unroll
    for (int nt = 0; nt < 4; ++nt) acc[mt][nt] = (f32x4){0.f, 0.f, 0.f, 0.f};
#pragma unroll 1
  for (int kc = 0; kc < 5; ++kc) {
#pragma unroll
    for (int it = 0; it < 4; ++it) {
      int c = tid + it * 256;              // 1024 chunks of 8 bf16
      int row = c >> 5, k8 = c & 31;
      bf16x8 v = *(const bf16x8*)(u + (size_t)(bM + row) * 1280 + kc * 256 + k8 * 8);
      int byteoff = row * 512 + ((k8 * 16) ^ ((row & 7) << 4));
      *(bf16x8*)((char*)Au + byteoff) = v;
    }
    __syncthreads();
#pragma unroll
    for (int kk = 0; kk < 8; ++kk) {
      int kidx = kk * 32 + lkg * 8;
      bf16x8 bfr[4];
#pragma unroll
      for (int nt = 0; nt < 4; ++nt)
        bfr[nt] = *(const bf16x8*)(W2 + (size_t)(w * 64 + nt * 16 + lr) * 1280 + kc * 256 + kidx);
#pragma unroll
      for (int mt = 0; mt < 2; ++mt) {
        int row = mt * 16 + lr;
        int byteoff = row * 512 + ((kidx * 2) ^ ((row & 7) << 4));
        bf16x8 a = *(const bf16x8*)((const char*)Au + byteoff);
#pragma unroll
        for (int nt = 0; nt < 4; ++nt)
          acc[mt][nt] = __builtin_amdgcn_mfma_f32_16x16x32_bf16(a, bfr[nt], acc[mt][nt], 0, 0, 0);
      }
    }
    __syncthreads();
  }
#pragma unroll
  for (int mt = 0; mt < 2; ++mt)
#pragma unroll
    for (int nt = 0; nt < 4; ++nt)
#pragma unroll
      for (int j = 0; j < 4; ++j) {
        int row = bM + mt * 16 + lkg * 4 + j;
        int col = w * 64 + nt * 16 + lr;
        out[(size_t)row * 256 + col] = (acc[mt][nt][j] + ego[(size_t)row * 256 + col]) * 0.5f;
      }
}

extern "C" void kernel_launch(void* const* d_in, const int* in_sizes, int n_in,
                              void* d_out, int out_size, void* d_ws, size_t ws_size,
                              hipStream_t stream) {
  const float* ego    = (const float*)d_in[0];
  const float* others = (const float*)d_in[1];
  const int*   mask   = (const int*)d_in[2];
  const float* wq  = (const float*)d_in[3];
  const float* wk  = (const float*)d_in[4];
  const float* wv  = (const float*)d_in[5];
  const float* wok = (const float*)d_in[6];
  const float* wov = (const float*)d_in[7];
  const float* wc  = (const float*)d_in[8];

  unsigned short* W1   = (unsigned short*)d_ws;                 // 1792*256
  unsigned short* W2   = W1 + 1792 * 256;                       // 256*1280
  unsigned short* qkv2 = W2 + 256 * 1280;                       // NB*1792
  unsigned short* u    = qkv2 + (size_t)NB * 1792;              // NB*1280

  float* res  = (float*)d_out;                                  // NB*256 f32
  float* attn = res + (size_t)NB * 256;                         // NB*128 f32

  hipLaunchKernelGGL(k0_all, dim3(2304), dim3(256), 0, stream,
                     wq, wk, wv, wok, wov, wc, W1, W2);
  hipLaunchKernelGGL(k1b,    dim3(512),  dim3(256), 0, stream, ego, W1, qkv2);
  hipLaunchKernelGGL(ks_attn, dim3(NB / 4), dim3(256), 0, stream,
                     others, mask, qkv2, u, attn);
  hipLaunchKernelGGL(k4_out, dim3(512),  dim3(256), 0, stream, u, W2, ego, res);
}